// Round 1
// baseline (465.057 us; speedup 1.0000x reference)
//
#include <hip/hip_runtime.h>

#define T_ 512
#define K_ 128
#define NEGV (-10000.0f)

__device__ __forceinline__ float bcast(float v, int lane) {
    return __uint_as_float(__builtin_amdgcn_readlane(__float_as_uint(v), lane));
}

// One block per batch element b. 128 threads = 2 waves.
// Lane l owns output rows r0=l, r1=64+l. Wave w owns j-range [64w, 64w+64).
// E = exp(trans) lives in registers: E0[jj]=exp(trans[r0][64w+jj]), E1 for r1.
// score state: lane l keeps score[r0], score[r1]; both waves redundantly
// compute all 128 new scores each step (own partial + other wave's partial
// exchanged via LDS), so the max-reduce is a pure within-wave butterfly.
__global__ __launch_bounds__(128, 1)
void crf_fwd(const float* __restrict__ h,
             const float* __restrict__ trans,
             const int* __restrict__ lengths,
             float* __restrict__ out)
{
    const int b   = blockIdx.x;
    const int tid = threadIdx.x;
    const int w   = tid >> 6;     // wave 0/1
    const int l   = tid & 63;     // lane
    const int r0  = l;
    const int r1  = 64 + l;
    const int jb  = w << 6;       // j-range base

    const float L2E = 1.4426950408889634f;
    const float LN2 = 0.6931471805599453f;

    // ---- preload E = exp(trans) fragments into registers (one-time) ----
    float E0[64], E1[64];
#pragma unroll
    for (int jj = 0; jj < 64; ++jj) {
        E0[jj] = exp2f(trans[r0 * K_ + jb + jj] * L2E);
        E1[jj] = exp2f(trans[r1 * K_ + jb + jj] * L2E);
    }

    __shared__ float part[2][2][64];

    const int len = lengths[b];
    const float* hb = h + (size_t)b * (T_ * K_);

    // init: score[START=127]=0, else NEG
    float score0 = NEGV;                          // r0 in 0..63, never 127
    float score1 = (r1 == K_ - 1) ? 0.0f : NEGV;
    float M = 0.0f;                               // true max of init scores
    // vp: lane j of wave w holds p[64w+j] = exp(score[64w+j] - M).
    // For wave0 that's this lane's score0; for wave1 this lane's score1.
    float vp = exp2f((((w == 0) ? score0 : score1) - M) * L2E);

    // h prefetch for t=0
    float hv0 = hb[r0];
    float hv1 = hb[r1];

    for (int t = 0; t < len; ++t) {
        // prefetch next step's h (clamped; harmless reload on last iter)
        const int tn = (t + 1 < len) ? t + 1 : t;
        const float hn0 = hb[tn * K_ + r0];
        const float hn1 = hb[tn * K_ + r1];

        // ---- matvec partials over this wave's j-half ----
        float a0 = 0.f, a1 = 0.f, c0 = 0.f, c1 = 0.f;
#pragma unroll
        for (int jj = 0; jj < 64; jj += 2) {
            const float p0 = bcast(vp, jj);
            const float p1 = bcast(vp, jj + 1);
            a0 = fmaf(p0, E0[jj],     a0);
            a1 = fmaf(p0, E1[jj],     a1);
            c0 = fmaf(p1, E0[jj + 1], c0);
            c1 = fmaf(p1, E1[jj + 1], c1);
        }
        const float acc0 = a0 + c0;
        const float acc1 = a1 + c1;

        // ---- cross-wave partial exchange ----
        part[w][0][l] = acc0;
        part[w][1][l] = acc1;
        __syncthreads();
        const float S0 = acc0 + part[1 - w][0][l];
        const float S1 = acc1 + part[1 - w][1][l];
        __syncthreads();   // protect 'part' before next iteration's writes

        // score' = log(S) + M + h
        const float s0n = fmaf(log2f(S0), LN2, M) + hv0;
        const float s1n = fmaf(log2f(S1), LN2, M) + hv1;

        // global max over all 128 rows: each wave holds all rows (2/lane)
        float m = fmaxf(s0n, s1n);
#pragma unroll
        for (int off = 32; off >= 1; off >>= 1)
            m = fmaxf(m, __shfl_xor(m, off, 64));

        score0 = s0n; score1 = s1n; M = m;
        vp = exp2f((((w == 0) ? score0 : score1) - M) * L2E);
        hv0 = hn0; hv1 = hn1;
    }

    // ---- out[b] = logsumexp_i(score[i] + trans[END=126][i]) ----
    const float v0 = score0 + trans[(K_ - 2) * K_ + r0];
    const float v1 = score1 + trans[(K_ - 2) * K_ + r1];
    float mm = fmaxf(v0, v1);
#pragma unroll
    for (int off = 32; off >= 1; off >>= 1)
        mm = fmaxf(mm, __shfl_xor(mm, off, 64));
    float e = exp2f((v0 - mm) * L2E) + exp2f((v1 - mm) * L2E);
#pragma unroll
    for (int off = 32; off >= 1; off >>= 1)
        e += __shfl_xor(e, off, 64);
    if (tid == 0) out[b] = fmaf(log2f(e), LN2, mm);
}

extern "C" void kernel_launch(void* const* d_in, const int* in_sizes, int n_in,
                              void* d_out, int out_size, void* d_ws, size_t ws_size,
                              hipStream_t stream) {
    const float* h       = (const float*)d_in[0];
    const float* trans   = (const float*)d_in[1];
    const int*   lengths = (const int*)d_in[2];
    float*       out     = (float*)d_out;
    const int B = in_sizes[2];   // 512
    crf_fwd<<<B, 128, 0, stream>>>(h, trans, lengths, out);
}

// Round 2
// 395.300 us; speedup vs baseline: 1.1765x; 1.1765x over previous
//
#include <hip/hip_runtime.h>

#define T_ 512
#define K_ 128
#define L2E 1.4426950408889634f
#define LN2 0.6931471805599453f

__device__ __forceinline__ float rl(float v, int lane) {
    return __uint_as_float(__builtin_amdgcn_readlane(__float_as_uint(v), lane));
}

// One block per batch element. 128 threads = 2 waves.
// Exponential-space recurrence: u[j] = exp(score[j] - CM).
// Wave w owns j in [64w, 64w+64): lane l holds u[64w+l].
// Per step: partial[i] = sum_{j in my half} E[i,j]*u[j] for rows r0=l, r1=64+l;
// cross-wave exchange of one partial per lane (1 barrier, parity dbuf);
// u'[row jb+l] = (own+other partial) * exp(h[t,row]) * (1/max_prev).
// No log/exp/max-reduce on the critical path; max butterfly overlaps matvec.
__global__ __launch_bounds__(128, 1)
void crf_fwd(const float* __restrict__ h,
             const float* __restrict__ trans,
             const int* __restrict__ lengths,
             float* __restrict__ out)
{
    const int b   = blockIdx.x;
    const int tid = threadIdx.x;
    const int w   = tid >> 6;
    const int l   = tid & 63;
    const int r0  = l;
    const int r1  = 64 + l;
    const int jb  = w << 6;

    // ---- one-time: E fragments, vectorized row loads ----
    float E0[64], E1[64];
    {
        const float4* t0 = reinterpret_cast<const float4*>(trans + r0 * K_ + jb);
        const float4* t1 = reinterpret_cast<const float4*>(trans + r1 * K_ + jb);
#pragma unroll
        for (int q = 0; q < 16; ++q) {
            float4 a = t0[q], c = t1[q];
            E0[4*q+0] = exp2f(a.x * L2E); E0[4*q+1] = exp2f(a.y * L2E);
            E0[4*q+2] = exp2f(a.z * L2E); E0[4*q+3] = exp2f(a.w * L2E);
            E1[4*q+0] = exp2f(c.x * L2E); E1[4*q+1] = exp2f(c.y * L2E);
            E1[4*q+2] = exp2f(c.z * L2E); E1[4*q+3] = exp2f(c.w * L2E);
        }
    }
    // final-transition weight for this lane's kept row (jb+l)
    const float tE = exp2f(trans[(K_ - 2) * K_ + jb + l] * L2E);

    __shared__ float xbuf[2][2][66]; // [parity][wave][0..63 partials, 64 max, 65 final]

    const int len = lengths[b];
    const float* hb = h + (size_t)b * (T_ * K_) + jb + l; // this lane's h column

    // state
    float u  = (jb + l == K_ - 1) ? 1.0f : 0.0f; // one-hot at START
    float CM = 0.0f;
    float ml = u;                                 // wave-local max of current u
    {   // full local max of initial u (wave1 has the 1, wave0 all zero)
#pragma unroll
        for (int off = 32; off >= 1; off >>= 1)
            ml = fmaxf(ml, __shfl_xor(ml, off, 64));
    }

    // h pipeline (raw values, 2 ahead)
    float hvA = hb[0];
    float hvB = (1 < len) ? hb[K_] : 0.0f;

    for (int t = 0; t < len; ++t) {
        const float ehv = exp2f(hvA * L2E);       // exp(h[t, jb+l])
        float hvC = 0.0f;
        if (t + 2 < len) hvC = hb[(size_t)(t + 2) * K_];

        // ---- matvec partials over my j-half, rows r0 and r1 ----
        float a0 = 0.f, a1 = 0.f, c0 = 0.f, c1 = 0.f;
#pragma unroll
        for (int jj = 0; jj < 64; jj += 2) {
            const float p0 = rl(u, jj);
            const float p1 = rl(u, jj + 1);
            a0 = fmaf(p0, E0[jj],     a0);
            a1 = fmaf(p0, E1[jj],     a1);
            c0 = fmaf(p1, E0[jj + 1], c0);
            c1 = fmaf(p1, E1[jj + 1], c1);
        }
        const float pKeep = (w == 0) ? (a0 + c0) : (a1 + c1); // row jb+l
        const float pGive = (w == 0) ? (a1 + c1) : (a0 + c0); // row (1-w)*64+l

        // ---- single-barrier parity-buffered exchange ----
        const int p = t & 1;
        xbuf[p][w][l] = pGive;
        if (l == 0) xbuf[p][w][64] = ml;   // local max of u entering this step
        __syncthreads();
        const float pOther = xbuf[p][1 - w][l];
        const float mg = fmaxf(ml, xbuf[p][1 - w][64]); // exact global max(u_t)
        const float cc = __builtin_amdgcn_rcpf(mg);

        // ---- update (the only ops after the barrier) ----
        u = (pKeep + pOther) * (ehv * cc);
        CM = fmaf(log2f(mg), LN2, CM);     // off critical path

        // local max butterfly for NEXT step (overlaps next matvec issue)
        float m2 = u;
#pragma unroll
        for (int off = 32; off >= 1; off >>= 1)
            m2 = fmaxf(m2, __shfl_xor(m2, off, 64));
        ml = m2;

        hvA = hvB; hvB = hvC;
    }

    // ---- out[b] = CM + log( sum_i u[i] * exp(trans[END,i]) ) ----
    float s = u * tE;
#pragma unroll
    for (int off = 32; off >= 1; off >>= 1)
        s += __shfl_xor(s, off, 64);
    xbuf[0][w][65] = s;
    __syncthreads();
    const float total = s + xbuf[0][1 - w][65];
    if (tid == 0) out[b] = fmaf(log2f(total), LN2, CM);
}

extern "C" void kernel_launch(void* const* d_in, const int* in_sizes, int n_in,
                              void* d_out, int out_size, void* d_ws, size_t ws_size,
                              hipStream_t stream) {
    const float* h       = (const float*)d_in[0];
    const float* trans   = (const float*)d_in[1];
    const int*   lengths = (const int*)d_in[2];
    float*       out     = (float*)d_out;
    const int B = in_sizes[2];   // 512
    crf_fwd<<<B, 128, 0, stream>>>(h, trans, lengths, out);
}

// Round 4
// 270.387 us; speedup vs baseline: 1.7200x; 1.4620x over previous
//
#include <hip/hip_runtime.h>

#define T_ 512
#define K_ 128
#define L2E 1.4426950408889634f
#define LN2 0.6931471805599453f

typedef _Float16 hv2 __attribute__((ext_vector_type(2)));

__device__ __forceinline__ int irl(int v, int lane) {
    return __builtin_amdgcn_readlane(v, lane);
}
__device__ __forceinline__ hv2 as_hv2(int i) { return __builtin_bit_cast(hv2, i); }
// cvt_pkrtz returns __fp16 ext_vector(2) — bit_cast to our hv2 / int
__device__ __forceinline__ hv2 pkh(float a, float b) {
    return __builtin_bit_cast(hv2, __builtin_amdgcn_cvt_pkrtz(a, b));
}
__device__ __forceinline__ int pk16(float a, float b) {
    return __builtin_bit_cast(int, __builtin_amdgcn_cvt_pkrtz(a, b));
}

#if __has_builtin(__builtin_amdgcn_fdot2)
#define FDOT2(a, b, c) __builtin_amdgcn_fdot2((a), (b), (c), false)
#else
__device__ __forceinline__ float fdot2_emu(hv2 a, hv2 b, float c) {
    return fmaf((float)a.x, (float)b.x, fmaf((float)a.y, (float)b.y, c));
}
#define FDOT2(a, b, c) fdot2_emu((a), (b), (c))
#endif

// wave64 max-reduce step via DPP (pure VALU, no lgkmcnt). u>=0 so 0-fill is safe.
#define DPPMAX(m, ctrl)                                                              \
    m = fmaxf(m, __int_as_float(__builtin_amdgcn_update_dpp(                          \
                     0, __float_as_int(m), (ctrl), 0xf, 0xf, true)))

// One wave (64 threads) per batch element. Lane l owns rows r0=2l, r1=2l+1.
// Exponential-space recurrence u[j] = exp(score[j] - CM), rescaled each step by an
// EXACT power of two (CM2 accumulates integer exponents in log2 space).
// Matvec: E packed f16 pairs over j in VGPRs; u broadcast as packed f16 pairs via
// readlane (lane p natively holds pair (u[2p],u[2p+1])); v_dot2_f32_f16 accumulate.
// No LDS, no barriers, no shfl in the steady-state loop.
__global__ __launch_bounds__(64, 1)
void crf_fwd(const float* __restrict__ h,
             const float* __restrict__ trans,
             const int* __restrict__ lengths,
             float* __restrict__ out)
{
    const int b  = blockIdx.x;
    const int l  = threadIdx.x;       // 0..63
    const int r0 = 2 * l, r1 = 2 * l + 1;

    // ---- one-time: E rows r0,r1 as packed f16 pairs over j ----
    hv2 Ea[64], Eb[64];
    {
        const float4* ta = reinterpret_cast<const float4*>(trans + r0 * K_);
        const float4* tb = reinterpret_cast<const float4*>(trans + r1 * K_);
#pragma unroll
        for (int q = 0; q < 32; ++q) {
            float4 x = ta[q];
            Ea[2 * q]     = pkh(exp2f(x.x * L2E), exp2f(x.y * L2E));
            Ea[2 * q + 1] = pkh(exp2f(x.z * L2E), exp2f(x.w * L2E));
            float4 y = tb[q];
            Eb[2 * q]     = pkh(exp2f(y.x * L2E), exp2f(y.y * L2E));
            Eb[2 * q + 1] = pkh(exp2f(y.z * L2E), exp2f(y.w * L2E));
        }
    }

    const int len = lengths[b];
    // this lane's h pair pointer; stride between t's = K_/2 float2's = 64
    const float2* hb = reinterpret_cast<const float2*>(h + (size_t)b * (T_ * K_) + r0);

    // state: u one-hot at START=127 (lane 63, r1)
    float u0 = 0.0f;
    float u1 = (l == 63) ? 1.0f : 0.0f;
    int   upk = pk16(u0, u1);
    float CM2 = 0.0f;                 // log2-space accumulated rescale exponents

    // h prefetch queue, 3 deep
    float2 q0 = hb[0];
    float2 q1 = (len > 1) ? hb[64]  : make_float2(0.f, 0.f);
    float2 q2 = (len > 2) ? hb[128] : make_float2(0.f, 0.f);

    for (int t = 0; t < len; ++t) {
        const int tf = (t + 3 < len) ? (t + 3) : (len - 1);
        const float2 q3 = hb[(size_t)tf * 64];

        const float eha = exp2f(q0.x * L2E);
        const float ehb = exp2f(q0.y * L2E);

        // ---- matvec: S[r0], S[r1] over all 128 j ----
        float A0 = 0.f, A1 = 0.f, A2 = 0.f, A3 = 0.f;
        float B0 = 0.f, B1 = 0.f, B2 = 0.f, B3 = 0.f;
#pragma unroll
        for (int p = 0; p < 64; p += 4) {
            const hv2 x0 = as_hv2(irl(upk, p));
            const hv2 x1 = as_hv2(irl(upk, p + 1));
            const hv2 x2 = as_hv2(irl(upk, p + 2));
            const hv2 x3 = as_hv2(irl(upk, p + 3));
            A0 = FDOT2(Ea[p],     x0, A0);
            B0 = FDOT2(Eb[p],     x0, B0);
            A1 = FDOT2(Ea[p + 1], x1, A1);
            B1 = FDOT2(Eb[p + 1], x1, B1);
            A2 = FDOT2(Ea[p + 2], x2, A2);
            B2 = FDOT2(Eb[p + 2], x2, B2);
            A3 = FDOT2(Ea[p + 3], x3, A3);
            B3 = FDOT2(Eb[p + 3], x3, B3);
        }
        const float ua = ((A0 + A1) + (A2 + A3)) * eha;
        const float ub = ((B0 + B1) + (B2 + B3)) * ehb;

        // ---- wave max via DPP (to lane 63), then exact pow2 rescale ----
        float m = fmaxf(ua, ub);
        DPPMAX(m, 0x111);   // row_shr:1
        DPPMAX(m, 0x112);   // row_shr:2
        DPPMAX(m, 0x114);   // row_shr:4
        DPPMAX(m, 0x118);   // row_shr:8
        DPPMAX(m, 0x142);   // row_bcast:15
        DPPMAX(m, 0x143);   // row_bcast:31
        const float mg = __int_as_float(irl(__float_as_int(m), 63));
        const int   e  = (int)(__float_as_uint(mg) >> 23) - 127;  // mg normal, >0
        const float c  = __int_as_float((127 - e) << 23);         // exact 2^-e
        CM2 += (float)e;

        u0 = ua * c;
        u1 = ub * c;
        upk = pk16(u0, u1);

        q0 = q1; q1 = q2; q2 = q3;
    }

    // ---- out[b] = ln2 * (CM2 + log2( sum_i u[i] * exp(trans[END,i]) )) ----
    const float tEa = exp2f(trans[(K_ - 2) * K_ + r0] * L2E);
    const float tEb = exp2f(trans[(K_ - 2) * K_ + r1] * L2E);
    float s = u0 * tEa + u1 * tEb;
#pragma unroll
    for (int off = 32; off >= 1; off >>= 1)
        s += __shfl_xor(s, off, 64);
    if (l == 0) out[b] = (CM2 + log2f(s)) * LN2;
}

extern "C" void kernel_launch(void* const* d_in, const int* in_sizes, int n_in,
                              void* d_out, int out_size, void* d_ws, size_t ws_size,
                              hipStream_t stream) {
    const float* h       = (const float*)d_in[0];
    const float* trans   = (const float*)d_in[1];
    const int*   lengths = (const int*)d_in[2];
    float*       out     = (float*)d_out;
    const int B = in_sizes[2];   // 512
    crf_fwd<<<B, 64, 0, stream>>>(h, trans, lengths, out);
}

// Round 5
// 244.369 us; speedup vs baseline: 1.9031x; 1.1065x over previous
//
#include <hip/hip_runtime.h>

#define T_ 512
#define K_ 128
#define L2E 1.4426950408889634f
#define LN2 0.6931471805599453f

typedef _Float16 hv2 __attribute__((ext_vector_type(2)));

__device__ __forceinline__ int irl(int v, int lane) {
    return __builtin_amdgcn_readlane(v, lane);
}
__device__ __forceinline__ hv2 as_hv2(int i) { return __builtin_bit_cast(hv2, i); }
__device__ __forceinline__ hv2 pkh(float a, float b) {
    return __builtin_bit_cast(hv2, __builtin_amdgcn_cvt_pkrtz(a, b));
}
__device__ __forceinline__ int pk16(float a, float b) {
    return __builtin_bit_cast(int, __builtin_amdgcn_cvt_pkrtz(a, b));
}

#if __has_builtin(__builtin_amdgcn_fdot2)
#define FDOT2(a, b, c) __builtin_amdgcn_fdot2((a), (b), (c), false)
#else
__device__ __forceinline__ float fdot2_emu(hv2 a, hv2 b, float c) {
    return fmaf((float)a.x, (float)b.x, fmaf((float)a.y, (float)b.y, c));
}
#define FDOT2(a, b, c) fdot2_emu((a), (b), (c))
#endif

// wave64 max-reduce step via DPP (pure VALU, no lgkmcnt). values >= 0 so 0-fill safe.
#define DPPMAX(m, ctrl)                                                     \
    m = fmaxf(m, __int_as_float(__builtin_amdgcn_update_dpp(                 \
                     0, __float_as_int(m), (ctrl), 0xf, 0xf, true)))

// One wave per batch element. Lane l owns rows 2l, 2l+1.
// Exponential-space recurrence with LAG-1 exact-pow2 rescale:
//   critical path per step = matvec -> sum tree -> 1 mul -> f16 pack.
// The max/exponent/exp2(h) work for step t+1 runs during step t's matvec.
// h loads use a static 4-slot pipeline (unroll-4): slot loaded at body t is
// first read at body t+3 (~1350 cyc issue->wait gap, covers cold HBM).
__global__ __launch_bounds__(64, 1)
void crf_fwd(const float* __restrict__ h,
             const float* __restrict__ trans,
             const int* __restrict__ lengths,
             float* __restrict__ out)
{
    const int b  = blockIdx.x;
    const int l  = threadIdx.x;       // 0..63
    const int r0 = 2 * l, r1 = 2 * l + 1;

    // ---- one-time: E rows r0,r1 as packed f16 pairs over j ----
    hv2 Ea[64], Eb[64];
    {
        const float4* ta = reinterpret_cast<const float4*>(trans + r0 * K_);
        const float4* tb = reinterpret_cast<const float4*>(trans + r1 * K_);
#pragma unroll
        for (int q = 0; q < 32; ++q) {
            float4 x = ta[q];
            Ea[2*q]   = pkh(exp2f(x.x*L2E), exp2f(x.y*L2E));
            Ea[2*q+1] = pkh(exp2f(x.z*L2E), exp2f(x.w*L2E));
            float4 y = tb[q];
            Eb[2*q]   = pkh(exp2f(y.x*L2E), exp2f(y.y*L2E));
            Eb[2*q+1] = pkh(exp2f(y.z*L2E), exp2f(y.w*L2E));
        }
    }

    const int len = lengths[b];
    const float2* hb = reinterpret_cast<const float2*>(h + (size_t)b*(T_*K_) + r0);

    // state: w = scaled exp(score), one-hot at START=127 (lane 63 hi)
    float w0 = 0.0f, w1 = (l == 63) ? 1.0f : 0.0f;
    int   wpk = pk16(w0, w1);
    float CM2 = 0.0f;      // applied log2 scale total
    float epend = 0.0f;    // exponent of the scale baked into current ehc

    auto ldh = [&](int tt) -> float2 {
        const int tc = (tt < len) ? tt : (len - 1);
        return hb[(size_t)tc * 64];
    };

    float2 s0 = ldh(0), s1 = ldh(1), s2 = ldh(2), s3 = ldh(3);
    float ehc0 = exp2f(s0.x * L2E);   // c_0 = 1 (max of init w is 1)
    float ehc1 = exp2f(s0.y * L2E);

    auto body = [&](int tt, float2& sload, const float2& snext) {
        sload = ldh(tt + 4);   // issue; not read until 3 bodies later

        // ---- matvec over all 128 j (critical path) ----
        float A0=0.f,A1=0.f,A2=0.f,A3=0.f,B0=0.f,B1=0.f,B2=0.f,B3=0.f;
#pragma unroll
        for (int p = 0; p < 64; p += 4) {
            const hv2 x0 = as_hv2(irl(wpk, p));
            const hv2 x1 = as_hv2(irl(wpk, p+1));
            const hv2 x2 = as_hv2(irl(wpk, p+2));
            const hv2 x3 = as_hv2(irl(wpk, p+3));
            A0 = FDOT2(Ea[p],   x0, A0);
            B0 = FDOT2(Eb[p],   x0, B0);
            A1 = FDOT2(Ea[p+1], x1, A1);
            B1 = FDOT2(Eb[p+1], x1, B1);
            A2 = FDOT2(Ea[p+2], x2, A2);
            B2 = FDOT2(Eb[p+2], x2, B2);
            A3 = FDOT2(Ea[p+3], x3, A3);
            B3 = FDOT2(Eb[p+3], x3, B3);
        }
        w0 = ((A0+A1)+(A2+A3)) * ehc0;   // ehc includes exp(h) and 2^-e (precomputed)
        w1 = ((B0+B1)+(B2+B3)) * ehc1;
        wpk = pk16(w0, w1);

        // ---- off-critical-path: build NEXT step's scale (lag-1, exact pow2) ----
        CM2 += epend;                      // account scale just applied
        float m = fmaxf(w0, w1);
        DPPMAX(m, 0x111); DPPMAX(m, 0x112); DPPMAX(m, 0x114);
        DPPMAX(m, 0x118); DPPMAX(m, 0x142); DPPMAX(m, 0x143);
        const float mg = __int_as_float(irl(__float_as_int(m), 63));
        const int   e  = (int)(__float_as_uint(mg) >> 23) - 127;
        epend = (float)e;
        const float cn = __int_as_float((127 - e) << 23);   // exact 2^-e
        ehc0 = exp2f(snext.x * L2E) * cn;
        ehc1 = exp2f(snext.y * L2E) * cn;
    };

    int t = 0;
    const int nfull = len & ~3;
    for (; t < nfull; t += 4) {
        body(t+0, s0, s1);
        body(t+1, s1, s2);
        body(t+2, s2, s3);
        body(t+3, s3, s0);
    }
    if (t     < len) body(t,   s0, s1);
    if (t + 1 < len) body(t+1, s1, s2);
    if (t + 2 < len) body(t+2, s2, s3);

    // ---- out[b] = ln2 * (CM2 + log2( sum_i w[i] * exp(trans[END,i]) )) ----
    const float tEa = exp2f(trans[(K_-2)*K_ + r0] * L2E);
    const float tEb = exp2f(trans[(K_-2)*K_ + r1] * L2E);
    float s = w0 * tEa + w1 * tEb;
#pragma unroll
    for (int off = 32; off >= 1; off >>= 1)
        s += __shfl_xor(s, off, 64);
    if (l == 0) out[b] = (CM2 + log2f(s)) * LN2;
}

extern "C" void kernel_launch(void* const* d_in, const int* in_sizes, int n_in,
                              void* d_out, int out_size, void* d_ws, size_t ws_size,
                              hipStream_t stream) {
    const float* h       = (const float*)d_in[0];
    const float* trans   = (const float*)d_in[1];
    const int*   lengths = (const int*)d_in[2];
    float*       out     = (float*)d_out;
    const int B = in_sizes[2];   // 512
    crf_fwd<<<B, 64, 0, stream>>>(h, trans, lengths, out);
}